// Round 2
// baseline (249.125 us; speedup 1.0000x reference)
//
#include <hip/hip_runtime.h>
#include <math.h>

#define KPOT 5

// One thread handles 8 consecutive rows (DIM=2):
//   x/noise/out chunk: 16 floats = 4 x float4 (64 B, 16B-aligned: 64*t)
//   gumbel chunk:      40 floats = 10 x float4 (160 B, 16B-aligned: 160*t)
// All 18 loads are issued before any use -> ~18 KB outstanding per wave,
// enough MLP to hide ~900-cycle HBM latency even at modest occupancy.
__global__ __launch_bounds__(256, 4) void lightsb_kernel(
    const float* __restrict__ x,
    const float* __restrict__ r,
    const float* __restrict__ log_S,
    const float* __restrict__ log_alpha,
    const float* __restrict__ gumbel,
    const float* __restrict__ noise,
    float* __restrict__ out,
    int n_rows)
{
    const int t = blockIdx.x * blockDim.x + threadIdx.x;
    const long long row0 = (long long)t * 8;
    if (row0 >= n_rows) return;

    float S0[KPOT], S1[KPOT], r0[KPOT], r1[KPOT], la[KPOT], q0[KPOT], q1[KPOT];

    if (row0 + 8 <= n_rows) {
        // ---- issue ALL global loads first (18 x float4) ----
        const float4* x4 = reinterpret_cast<const float4*>(x + row0 * 2);
        const float4* n4 = reinterpret_cast<const float4*>(noise + row0 * 2);
        const float4* g4 = reinterpret_cast<const float4*>(gumbel + row0 * 5);

        float4 xv[4], nv[4], gv[10];
#pragma unroll
        for (int i = 0; i < 4; ++i) xv[i] = x4[i];
#pragma unroll
        for (int i = 0; i < 10; ++i) gv[i] = g4[i];
#pragma unroll
        for (int i = 0; i < 4; ++i) nv[i] = n4[i];

        // ---- param setup overlaps load latency (no dependence on loads) ----
#pragma unroll
        for (int k = 0; k < KPOT; ++k) {
            float s0 = expf(log_S[2 * k + 0]);
            float s1 = expf(log_S[2 * k + 1]);
            S0[k] = s0;  S1[k] = s1;
            r0[k] = r[2 * k + 0];  r1[k] = r[2 * k + 1];
            la[k] = log_alpha[k];
            q0[k] = sqrtf(s0);  q1[k] = sqrtf(s1);   // EPS = 1.0
        }

        const float* xf = reinterpret_cast<const float*>(xv);
        const float* nf = reinterpret_cast<const float*>(nv);
        const float* gf = reinterpret_cast<const float*>(gv);
        float4 ov[4];
        float* of = reinterpret_cast<float*>(ov);

#pragma unroll
        for (int j = 0; j < 8; ++j) {
            float x0 = xf[2 * j + 0];
            float x1 = xf[2 * j + 1];
            float u0 = 0.5f * x0 * x0;
            float u1 = 0.5f * x1 * x1;

            // logits_k = S0*u0 + S1*u1 + r0*x0 + r1*x1 + la   (EPS = 1)
            float best = fmaf(S0[0], u0, fmaf(S1[0], u1,
                         fmaf(r0[0], x0, fmaf(r1[0], x1, la[0] + gf[5 * j + 0]))));
            float bS0 = S0[0], bS1 = S1[0];
            float br0 = r0[0], br1 = r1[0];
            float bq0 = q0[0], bq1 = q1[0];
#pragma unroll
            for (int k = 1; k < KPOT; ++k) {
                float s = fmaf(S0[k], u0, fmaf(S1[k], u1,
                          fmaf(r0[k], x0, fmaf(r1[k], x1, la[k] + gf[5 * j + k]))));
                bool c = s > best;          // strict > keeps first max (jnp.argmax)
                best = c ? s : best;
                bS0 = c ? S0[k] : bS0;
                bS1 = c ? S1[k] : bS1;
                br0 = c ? r0[k] : br0;
                br1 = c ? r1[k] : br1;
                bq0 = c ? q0[k] : bq0;
                bq1 = c ? q1[k] : bq1;
            }
            of[2 * j + 0] = fmaf(bS0, x0, fmaf(bq0, nf[2 * j + 0], br0));
            of[2 * j + 1] = fmaf(bS1, x1, fmaf(bq1, nf[2 * j + 1], br1));
        }

        float4* o4 = reinterpret_cast<float4*>(out + row0 * 2);
#pragma unroll
        for (int i = 0; i < 4; ++i) o4[i] = ov[i];
    } else {
        // ---- scalar tail (only if n_rows % 8 != 0) ----
#pragma unroll
        for (int k = 0; k < KPOT; ++k) {
            float s0 = expf(log_S[2 * k + 0]);
            float s1 = expf(log_S[2 * k + 1]);
            S0[k] = s0;  S1[k] = s1;
            r0[k] = r[2 * k + 0];  r1[k] = r[2 * k + 1];
            la[k] = log_alpha[k];
            q0[k] = sqrtf(s0);  q1[k] = sqrtf(s1);
        }
        for (long long row = row0; row < n_rows; ++row) {
            float x0 = x[row * 2 + 0];
            float x1 = x[row * 2 + 1];
            float u0 = 0.5f * x0 * x0;
            float u1 = 0.5f * x1 * x1;
            float best = fmaf(S0[0], u0, fmaf(S1[0], u1,
                         fmaf(r0[0], x0, fmaf(r1[0], x1, la[0] + gumbel[row * 5 + 0]))));
            int bidx = 0;
#pragma unroll
            for (int k = 1; k < KPOT; ++k) {
                float s = fmaf(S0[k], u0, fmaf(S1[k], u1,
                          fmaf(r0[k], x0, fmaf(r1[k], x1, la[k] + gumbel[row * 5 + k]))));
                if (s > best) { best = s; bidx = k; }
            }
            float n0 = noise[row * 2 + 0];
            float n1 = noise[row * 2 + 1];
            out[row * 2 + 0] = fmaf(S0[bidx], x0, fmaf(q0[bidx], n0, r0[bidx]));
            out[row * 2 + 1] = fmaf(S1[bidx], x1, fmaf(q1[bidx], n1, r1[bidx]));
        }
    }
}

extern "C" void kernel_launch(void* const* d_in, const int* in_sizes, int n_in,
                              void* d_out, int out_size, void* d_ws, size_t ws_size,
                              hipStream_t stream) {
    const float* x         = (const float*)d_in[0];
    const float* r         = (const float*)d_in[1];
    const float* log_S     = (const float*)d_in[2];
    const float* log_alpha = (const float*)d_in[3];
    const float* gumbel    = (const float*)d_in[4];
    const float* noise     = (const float*)d_in[5];
    float* out = (float*)d_out;

    const int n_rows = in_sizes[0] / 2;            // DIM = 2
    const int n_threads = (n_rows + 7) / 8;        // 8 rows per thread
    const int block = 256;
    const int grid = (n_threads + block - 1) / block;

    lightsb_kernel<<<grid, block, 0, stream>>>(x, r, log_S, log_alpha,
                                               gumbel, noise, out, n_rows);
}

// Round 3
// 188.673 us; speedup vs baseline: 1.3204x; 1.3204x over previous
//
#include <hip/hip_runtime.h>
#include <math.h>

#define KPOT 5
#define ROWS_PER_BLOCK 1024                      // 256 threads x 4 rows
#define GUMBEL_FLOATS (ROWS_PER_BLOCK * KPOT)    // 5120 floats = 20 KB LDS

// Fully-coalesced design:
//   x/noise/out: one float4 per (thread, pair) = exactly 2 rows, lane i <-> base+16i.
//   gumbel: staged to LDS with coalesced float4 loads + ds_write_b128,
//           then per-row reads from LDS (cheap, conflicts <= 4-way).
__global__ __launch_bounds__(256) void lightsb_kernel(
    const float* __restrict__ x,
    const float* __restrict__ r,
    const float* __restrict__ log_S,
    const float* __restrict__ log_alpha,
    const float* __restrict__ gumbel,
    const float* __restrict__ noise,
    float* __restrict__ out,
    int n_rows)
{
    __shared__ float gsh[GUMBEL_FLOATS];

    const int t = threadIdx.x;
    const long long blockRow0 = (long long)blockIdx.x * ROWS_PER_BLOCK;

    // Per-k constants (uniform, L1-cached broadcast; overlaps load latency).
    float S0[KPOT], S1[KPOT], r0[KPOT], r1[KPOT], la[KPOT], q0[KPOT], q1[KPOT];

    if (blockRow0 + ROWS_PER_BLOCK <= n_rows) {
        // ---- issue compute-stream loads (fully coalesced float4) ----
        const float4* x4 = reinterpret_cast<const float4*>(x) + blockRow0 / 2;
        const float4* n4 = reinterpret_cast<const float4*>(noise) + blockRow0 / 2;
        float4 xa = x4[t];            // rows 2t, 2t+1        (local)
        float4 xb = x4[256 + t];      // rows 512+2t, 512+2t+1
        float4 na = n4[t];
        float4 nb = n4[256 + t];

        // ---- stage gumbel tile into LDS (coalesced global, conflict-free LDS) ----
        const float4* g4 = reinterpret_cast<const float4*>(gumbel) + blockRow0 * KPOT / 4;
        float4* gsh4 = reinterpret_cast<float4*>(gsh);
#pragma unroll
        for (int j = 0; j < 5; ++j)
            gsh4[j * 256 + t] = g4[j * 256 + t];

        // ---- param setup while loads are in flight ----
#pragma unroll
        for (int k = 0; k < KPOT; ++k) {
            float s0 = expf(log_S[2 * k + 0]);
            float s1 = expf(log_S[2 * k + 1]);
            S0[k] = s0;  S1[k] = s1;
            r0[k] = r[2 * k + 0];  r1[k] = r[2 * k + 1];
            la[k] = log_alpha[k];
            q0[k] = sqrtf(s0);  q1[k] = sqrtf(s1);   // EPS = 1.0
        }

        __syncthreads();

        float4* o4 = reinterpret_cast<float4*>(out) + blockRow0 / 2;

#pragma unroll
        for (int p = 0; p < 2; ++p) {
            const float4 xv = (p == 0) ? xa : xb;
            const float4 nv = (p == 0) ? na : nb;
            const int lr0 = p * 512 + 2 * t;           // local row of .x/.y
            const float* g0 = &gsh[lr0 * KPOT];        // 10 consecutive floats
            float ov[4];

#pragma unroll
            for (int h = 0; h < 2; ++h) {              // two rows in this float4
                const float xx0 = (h == 0) ? xv.x : xv.z;
                const float xx1 = (h == 0) ? xv.y : xv.w;
                const float nn0 = (h == 0) ? nv.x : nv.z;
                const float nn1 = (h == 0) ? nv.y : nv.w;
                const float* g = g0 + h * KPOT;

                const float u0 = 0.5f * xx0 * xx0;
                const float u1 = 0.5f * xx1 * xx1;

                float best = fmaf(S0[0], u0, fmaf(S1[0], u1,
                             fmaf(r0[0], xx0, fmaf(r1[0], xx1, la[0] + g[0]))));
                float bS0 = S0[0], bS1 = S1[0];
                float br0 = r0[0], br1 = r1[0];
                float bq0 = q0[0], bq1 = q1[0];
#pragma unroll
                for (int k = 1; k < KPOT; ++k) {
                    float s = fmaf(S0[k], u0, fmaf(S1[k], u1,
                              fmaf(r0[k], xx0, fmaf(r1[k], xx1, la[k] + g[k]))));
                    bool c = s > best;     // strict > keeps first max (jnp.argmax)
                    best = c ? s : best;
                    bS0 = c ? S0[k] : bS0;
                    bS1 = c ? S1[k] : bS1;
                    br0 = c ? r0[k] : br0;
                    br1 = c ? r1[k] : br1;
                    bq0 = c ? q0[k] : bq0;
                    bq1 = c ? q1[k] : bq1;
                }
                ov[2 * h + 0] = fmaf(bS0, xx0, fmaf(bq0, nn0, br0));
                ov[2 * h + 1] = fmaf(bS1, xx1, fmaf(bq1, nn1, br1));
            }
            o4[p * 256 + t] = make_float4(ov[0], ov[1], ov[2], ov[3]);
        }
    } else {
        // ---- scalar fallback for a partial last block (n_rows % 1024 != 0) ----
#pragma unroll
        for (int k = 0; k < KPOT; ++k) {
            float s0 = expf(log_S[2 * k + 0]);
            float s1 = expf(log_S[2 * k + 1]);
            S0[k] = s0;  S1[k] = s1;
            r0[k] = r[2 * k + 0];  r1[k] = r[2 * k + 1];
            la[k] = log_alpha[k];
            q0[k] = sqrtf(s0);  q1[k] = sqrtf(s1);
        }
        for (long long row = blockRow0 + t; row < n_rows; row += 256) {
            float x0 = x[row * 2 + 0];
            float x1 = x[row * 2 + 1];
            float u0 = 0.5f * x0 * x0;
            float u1 = 0.5f * x1 * x1;
            float best = fmaf(S0[0], u0, fmaf(S1[0], u1,
                         fmaf(r0[0], x0, fmaf(r1[0], x1, la[0] + gumbel[row * KPOT + 0]))));
            int bidx = 0;
#pragma unroll
            for (int k = 1; k < KPOT; ++k) {
                float s = fmaf(S0[k], u0, fmaf(S1[k], u1,
                          fmaf(r0[k], x0, fmaf(r1[k], x1, la[k] + gumbel[row * KPOT + k]))));
                if (s > best) { best = s; bidx = k; }
            }
            float n0 = noise[row * 2 + 0];
            float n1 = noise[row * 2 + 1];
            out[row * 2 + 0] = fmaf(S0[bidx], x0, fmaf(q0[bidx], n0, r0[bidx]));
            out[row * 2 + 1] = fmaf(S1[bidx], x1, fmaf(q1[bidx], n1, r1[bidx]));
        }
    }
}

extern "C" void kernel_launch(void* const* d_in, const int* in_sizes, int n_in,
                              void* d_out, int out_size, void* d_ws, size_t ws_size,
                              hipStream_t stream) {
    const float* x         = (const float*)d_in[0];
    const float* r         = (const float*)d_in[1];
    const float* log_S     = (const float*)d_in[2];
    const float* log_alpha = (const float*)d_in[3];
    const float* gumbel    = (const float*)d_in[4];
    const float* noise     = (const float*)d_in[5];
    float* out = (float*)d_out;

    const int n_rows = in_sizes[0] / 2;                      // DIM = 2
    const int grid = (n_rows + ROWS_PER_BLOCK - 1) / ROWS_PER_BLOCK;

    lightsb_kernel<<<grid, 256, 0, stream>>>(x, r, log_S, log_alpha,
                                             gumbel, noise, out, n_rows);
}